// Round 5
// baseline (217.682 us; speedup 1.0000x reference)
//
#include <hip/hip_runtime.h>
#include <math.h>

#define SS 2048
#define EE 1024

using bf16x8 = __attribute__((ext_vector_type(8))) short;
using f32x4  = __attribute__((ext_vector_type(4))) float;

// RTNE (used in prep only, cold)
__device__ inline short f2bf(float x) {
    unsigned u = __builtin_bit_cast(unsigned, x);
    return (short)((u + 0x7fffu + ((u >> 16) & 1u)) >> 16);
}
// round-half-up, 2 VALU
__device__ inline short f2bf_r(float x) {
    return (short)((__builtin_bit_cast(unsigned, x) + 0x8000u) >> 16);
}
// pack 2 floats -> 2 bf16 in one dword: 2 adds + 1 v_perm
__device__ inline unsigned pk_bf16(float a, float b) {
    unsigned ua = __builtin_bit_cast(unsigned, a) + 0x8000u;
    unsigned ub = __builtin_bit_cast(unsigned, b) + 0x8000u;
    return __builtin_amdgcn_perm(ub, ua, 0x07060302u);  // lo16=hi(ua), hi16=hi(ub)
}

// ---------- weight prep + rope table ----------
// Wall[768][1024] bf16 B^T: 0-255 = group-summed Wq * 0.125*log2e, 256-511 = Wk, 512-767 = Wv.
// Wo4[1024][256] = 0.25*Wo^T. RT[s*32+ii] = {cos,sin}.
__global__ __launch_bounds__(256) void prep_weights(const float* __restrict__ Wq,
                                                    const float* __restrict__ Wk,
                                                    const float* __restrict__ Wv,
                                                    const float* __restrict__ Wo,
                                                    short* __restrict__ Wall,
                                                    short* __restrict__ Wo4,
                                                    float2* __restrict__ RT) {
    int idx = blockIdx.x * 256 + threadIdx.x;   // 262144 = 256 c * 1024 e
    int c = idx >> 10, e = idx & 1023;
    int h = c >> 6, d = c & 63;
    const float* p = Wq + (size_t)e * 1024 + h * 256 + d;   // Wq[e][h*4+g][d]
    Wall[(size_t)c * 1024 + e] = f2bf(0.18033688011112042f * (p[0] + p[64] + p[128] + p[192]));
    Wall[(size_t)(256 + c) * 1024 + e] = f2bf(Wk[(size_t)e * 256 + c]);
    Wall[(size_t)(512 + c) * 1024 + e] = f2bf(Wv[(size_t)e * 256 + c]);
    Wo4[(size_t)e * 256 + c] = f2bf(0.25f * Wo[(size_t)d * 1024 + e]);
    if (idx < 65536) {
        int s = idx >> 5, ii = idx & 31;
        float freq = __expf(-(float)ii * (9.210340371976184f / 32.0f));
        float sn, cs;
        sincosf((float)s * freq, &sn, &cs);
        RT[idx] = (float2){cs, sn};
    }
}

// ---------- fused Q/K/V projection, V written pre-transposed ----------
__global__ __launch_bounds__(256) void proj_kernel(const float* __restrict__ q,
                                                   const float* __restrict__ kv,
                                                   const short* __restrict__ Wall,
                                                   const float2* __restrict__ RT,
                                                   short* __restrict__ Qb,
                                                   short* __restrict__ Kb,
                                                   short* __restrict__ Vt) {
    __shared__ short As[128][72];
    __shared__ short Bs[64][72];
    int tid = threadIdx.x;
    int wave = tid >> 6, lane = tid & 63, quad = lane >> 4, c16 = lane & 15;
    int wm = wave >> 1, wn = wave & 1;
    int m0 = blockIdx.x * 128, n0 = blockIdx.y * 64;
    const float* A = (n0 < 256) ? q : kv;

    f32x4 acc[4][2];
    #pragma unroll
    for (int i = 0; i < 4; i++)
        #pragma unroll
        for (int j = 0; j < 2; j++) acc[i][j] = (f32x4){0.f, 0.f, 0.f, 0.f};

    for (int k0 = 0; k0 < 1024; k0 += 64) {
        #pragma unroll
        for (int i = 0; i < 8; i++) {
            int id = i * 256 + tid, r = id >> 4, ch = id & 15;
            float4 v = *(const float4*)&A[(size_t)(m0 + r) * 1024 + k0 + ch * 4];
            uint2 u;
            u.x = pk_bf16(v.x, v.y);
            u.y = pk_bf16(v.z, v.w);
            *(uint2*)&As[r][ch * 4] = u;
        }
        #pragma unroll
        for (int i = 0; i < 2; i++) {
            int id = i * 256 + tid, r = id >> 3, ch = id & 7;
            *(int4*)&Bs[r][ch * 8] =
                *(const int4*)&Wall[(size_t)(n0 + r) * 1024 + k0 + ch * 8];
        }
        __syncthreads();
        #pragma unroll
        for (int ks = 0; ks < 64; ks += 32) {
            bf16x8 af[4], bfr[2];
            #pragma unroll
            for (int mt = 0; mt < 4; mt++)
                af[mt] = *(const bf16x8*)&As[wm * 64 + mt * 16 + c16][ks + quad * 8];
            #pragma unroll
            for (int nt = 0; nt < 2; nt++)
                bfr[nt] = *(const bf16x8*)&Bs[wn * 32 + nt * 16 + c16][ks + quad * 8];
            #pragma unroll
            for (int mt = 0; mt < 4; mt++)
                #pragma unroll
                for (int nt = 0; nt < 2; nt++)
                    acc[mt][nt] = __builtin_amdgcn_mfma_f32_16x16x32_bf16(
                        af[mt], bfr[nt], acc[mt][nt], 0, 0, 0);
        }
        __syncthreads();
    }
    #pragma unroll
    for (int mt = 0; mt < 4; mt++) {
        #pragma unroll
        for (int nt = 0; nt < 2; nt++) {
            int col = n0 + wn * 32 + nt * 16 + c16;
            int rowb = m0 + wm * 64 + mt * 16 + quad * 4;
            f32x4 v = acc[mt][nt];
            if (col < 512) {                       // Q or K: rope via table
                short* dst = (col < 256) ? (Qb + col) : (Kb + col - 256);
                int ii = (col & 63) >> 1;
                float sgn = (lane & 1) ? 1.0f : -1.0f;
                #pragma unroll
                for (int r = 0; r < 4; r++) {
                    int row = rowb + r;
                    float2 cs = RT[(row & (SS - 1)) * 32 + ii];
                    float other = __shfl_xor(v[r], 1);
                    dst[(size_t)row * 256] = f2bf_r(v[r] * cs.x + sgn * cs.y * other);
                }
            } else {                               // V: write transposed Vt[bh*64+d][s]
                int c = col - 512;                 // h*64+d
                int b = rowb >> 11, s0 = rowb & (SS - 1);
                uint2 u;
                u.x = pk_bf16(v[0], v[1]);
                u.y = pk_bf16(v[2], v[3]);
                *(uint2*)&Vt[((size_t)(b * 256 + c)) * SS + s0] = u;
            }
        }
    }
}

// ---------- MFMA flash attention, static max, K-split x2 ----------
__global__ __launch_bounds__(256) void attn_kernel(const short* __restrict__ Qb,
                                                   const short* __restrict__ Kb,
                                                   const short* __restrict__ Vt,
                                                   float* __restrict__ Opart,
                                                   float* __restrict__ Lpart) {
    __shared__ short Qs[64][72], Ks[64][72], Vs[64][72];
    __shared__ short Ps[4][16][72];
    int tid = threadIdx.x;
    int wave = tid >> 6, lane = tid & 63, quad = lane >> 4, c16 = lane & 15;
    int qt = blockIdx.x, bh = blockIdx.y, kc = blockIdx.z;
    int q0 = qt * 64;
    size_t qkbase = (size_t)(bh >> 2) * SS * 256 + (bh & 3) * 64;
    size_t vtbase = (size_t)(bh * 64) * SS;
    size_t pbase  = (size_t)(kc * 16 + bh) * SS;

    #pragma unroll
    for (int i = 0; i < 2; i++) {
        int id = i * 256 + tid, r = id >> 3, ch = id & 7;
        *(int4*)&Qs[r][ch * 8] = *(const int4*)&Qb[qkbase + (size_t)(q0 + r) * 256 + ch * 8];
    }
    __syncthreads();
    bf16x8 aq0 = *(const bf16x8*)&Qs[wave * 16 + c16][quad * 8];
    bf16x8 aq1 = *(const bf16x8*)&Qs[wave * 16 + c16][32 + quad * 8];

    float lsum[4] = {0.f, 0.f, 0.f, 0.f};
    f32x4 o[4];
    #pragma unroll
    for (int dt = 0; dt < 4; dt++) o[dt] = (f32x4){0.f, 0.f, 0.f, 0.f};

    for (int kt = 0; kt < 16; kt++) {
        int a0 = kc * 1024 + kt * 64;
        __syncthreads();
        #pragma unroll
        for (int i = 0; i < 2; i++) {
            int id = i * 256 + tid, r = id >> 3, ch = id & 7;
            *(int4*)&Ks[r][ch * 8] =
                *(const int4*)&Kb[qkbase + (size_t)(a0 + r) * 256 + ch * 8];
            *(int4*)&Vs[r][ch * 8] =
                *(const int4*)&Vt[vtbase + (size_t)r * SS + a0 + ch * 8];
        }
        __syncthreads();
        f32x4 sv[4];
        #pragma unroll
        for (int nt = 0; nt < 4; nt++) sv[nt] = (f32x4){0.f, 0.f, 0.f, 0.f};
        #pragma unroll
        for (int nt = 0; nt < 4; nt++) {
            bf16x8 bk0 = *(const bf16x8*)&Ks[nt * 16 + c16][quad * 8];
            bf16x8 bk1 = *(const bf16x8*)&Ks[nt * 16 + c16][32 + quad * 8];
            sv[nt] = __builtin_amdgcn_mfma_f32_16x16x32_bf16(aq0, bk0, sv[nt], 0, 0, 0);
            sv[nt] = __builtin_amdgcn_mfma_f32_16x16x32_bf16(aq1, bk1, sv[nt], 0, 0, 0);
        }
        #pragma unroll
        for (int nt = 0; nt < 4; nt++)
            #pragma unroll
            for (int r = 0; r < 4; r++) sv[nt][r] = __builtin_exp2f(sv[nt][r]);
        #pragma unroll
        for (int r = 0; r < 4; r++)
            lsum[r] += (sv[0][r] + sv[1][r]) + (sv[2][r] + sv[3][r]);
        #pragma unroll
        for (int nt = 0; nt < 4; nt++)
            #pragma unroll
            for (int r = 0; r < 4; r++)
                Ps[wave][quad * 4 + r][nt * 16 + c16] = f2bf_r(sv[nt][r]);
        #pragma unroll
        for (int ks = 0; ks < 64; ks += 32) {
            bf16x8 ap = *(const bf16x8*)&Ps[wave][c16][ks + quad * 8];
            #pragma unroll
            for (int dt = 0; dt < 4; dt++) {
                bf16x8 bv = *(const bf16x8*)&Vs[dt * 16 + c16][ks + quad * 8];
                o[dt] = __builtin_amdgcn_mfma_f32_16x16x32_bf16(ap, bv, o[dt], 0, 0, 0);
            }
        }
    }
    #pragma unroll
    for (int off = 1; off < 16; off <<= 1)
        #pragma unroll
        for (int r = 0; r < 4; r++) lsum[r] += __shfl_xor(lsum[r], off);
    #pragma unroll
    for (int dt = 0; dt < 4; dt++)
        #pragma unroll
        for (int r = 0; r < 4; r++) {
            int row = q0 + wave * 16 + quad * 4 + r;
            Opart[(pbase + row) * 64 + dt * 16 + c16] = o[dt][r];
        }
    if (c16 == 0)
        #pragma unroll
        for (int r = 0; r < 4; r++)
            Lpart[pbase + q0 + wave * 16 + quad * 4 + r] = lsum[r];
}

// ---------- output projection with fused K-split combine ----------
__global__ __launch_bounds__(256) void outproj_kernel(const float* __restrict__ Op,
                                                      const float* __restrict__ Lp,
                                                      const short* __restrict__ Wo4,
                                                      float* __restrict__ out) {
    __shared__ short As[128][72];
    __shared__ short Bs[128][72];
    int tid = threadIdx.x;
    int wave = tid >> 6, lane = tid & 63, quad = lane >> 4, c16 = lane & 15;
    int wm = wave >> 1, wn = wave & 1;
    int m0 = blockIdx.x * 128, n0 = blockIdx.y * 128;

    f32x4 acc[4][4];
    #pragma unroll
    for (int i = 0; i < 4; i++)
        #pragma unroll
        for (int j = 0; j < 4; j++) acc[i][j] = (f32x4){0.f, 0.f, 0.f, 0.f};

    for (int k0 = 0; k0 < 256; k0 += 64) {
        int h = k0 >> 6;
        #pragma unroll
        for (int i = 0; i < 8; i++) {
            int id = i * 256 + tid, r = id >> 4, ch = id & 15;
            int row = m0 + r, b = row >> 11, s = row & (SS - 1);
            int bh = b * 4 + h;
            size_t pidx = ((size_t)bh * SS + s) * 64 + ch * 4;
            float4 a = *(const float4*)&Op[pidx];
            float4 c = *(const float4*)&Op[pidx + (size_t)16 * SS * 64];
            float l = Lp[(size_t)bh * SS + s] + Lp[(size_t)(16 + bh) * SS + s];
            float rl = __builtin_amdgcn_rcpf(l);
            uint2 u;
            u.x = pk_bf16((a.x + c.x) * rl, (a.y + c.y) * rl);
            u.y = pk_bf16((a.z + c.z) * rl, (a.w + c.w) * rl);
            *(uint2*)&As[r][ch * 4] = u;
        }
        #pragma unroll
        for (int i = 0; i < 4; i++) {
            int id = i * 256 + tid, r = id >> 3, ch = id & 7;
            *(int4*)&Bs[r][ch * 8] =
                *(const int4*)&Wo4[(size_t)(n0 + r) * 256 + k0 + ch * 8];
        }
        __syncthreads();
        #pragma unroll
        for (int ks = 0; ks < 64; ks += 32) {
            bf16x8 af[4], bfr[4];
            #pragma unroll
            for (int mt = 0; mt < 4; mt++)
                af[mt] = *(const bf16x8*)&As[wm * 64 + mt * 16 + c16][ks + quad * 8];
            #pragma unroll
            for (int nt = 0; nt < 4; nt++)
                bfr[nt] = *(const bf16x8*)&Bs[wn * 64 + nt * 16 + c16][ks + quad * 8];
            #pragma unroll
            for (int mt = 0; mt < 4; mt++)
                #pragma unroll
                for (int nt = 0; nt < 4; nt++)
                    acc[mt][nt] = __builtin_amdgcn_mfma_f32_16x16x32_bf16(
                        af[mt], bfr[nt], acc[mt][nt], 0, 0, 0);
        }
        __syncthreads();
    }
    #pragma unroll
    for (int mt = 0; mt < 4; mt++)
        #pragma unroll
        for (int nt = 0; nt < 4; nt++) {
            int col = n0 + wn * 64 + nt * 16 + c16;
            int rowb = m0 + wm * 64 + mt * 16 + quad * 4;
            #pragma unroll
            for (int r = 0; r < 4; r++)
                out[(size_t)(rowb + r) * 1024 + col] = acc[mt][nt][r];
        }
}

extern "C" void kernel_launch(void* const* d_in, const int* in_sizes, int n_in,
                              void* d_out, int out_size, void* d_ws, size_t ws_size,
                              hipStream_t stream) {
    const float* q  = (const float*)d_in[0];
    const float* kv = (const float*)d_in[1];
    const float* Wq = (const float*)d_in[2];
    const float* Wk = (const float*)d_in[3];
    const float* Wv = (const float*)d_in[4];
    const float* Wo = (const float*)d_in[5];
    float* out = (float*)d_out;

    short* Qb    = (short*)d_ws;           // 2097152 bf16
    short* Kb    = Qb + 2097152;           // 2097152
    short* Vt    = Kb + 2097152;           // 2097152 (pre-transposed [bh*64+d][s])
    short* Wall  = Vt + 2097152;           // 786432
    short* Wo4   = Wall + 786432;          // 262144
    float2* RT   = (float2*)(Wo4 + 262144);    // 65536 float2 (offset 14.7MB, aligned)
    float* Opart = (float*)(RT + 65536);   // 4194304 fp32
    float* Lpart = Opart + 4194304;        // 65536 fp32
    // total ws use: ~32.5 MB

    prep_weights<<<1024, 256, 0, stream>>>(Wq, Wk, Wv, Wo, Wall, Wo4, RT);

    proj_kernel<<<dim3(64, 12), 256, 0, stream>>>(q, kv, Wall, RT, Qb, Kb, Vt);

    attn_kernel<<<dim3(32, 16, 2), 256, 0, stream>>>(Qb, Kb, Vt, Opart, Lpart);

    outproj_kernel<<<dim3(64, 8), 256, 0, stream>>>(Opart, Lpart, Wo4, out);
}

// Round 6
// 210.890 us; speedup vs baseline: 1.0322x; 1.0322x over previous
//
#include <hip/hip_runtime.h>
#include <math.h>

#define SS 2048
#define EE 1024

using bf16x8 = __attribute__((ext_vector_type(8))) short;
using f32x4  = __attribute__((ext_vector_type(4))) float;

// RTNE (prep only, cold)
__device__ inline short f2bf(float x) {
    unsigned u = __builtin_bit_cast(unsigned, x);
    return (short)((u + 0x7fffu + ((u >> 16) & 1u)) >> 16);
}
// round-half-up, 2 VALU
__device__ inline short f2bf_r(float x) {
    return (short)((__builtin_bit_cast(unsigned, x) + 0x8000u) >> 16);
}
// pack 2 floats -> 2 bf16 in one dword: 2 adds + 1 v_perm
__device__ inline unsigned pk_bf16(float a, float b) {
    unsigned ua = __builtin_bit_cast(unsigned, a) + 0x8000u;
    unsigned ub = __builtin_bit_cast(unsigned, b) + 0x8000u;
    return __builtin_amdgcn_perm(ub, ua, 0x07060302u);
}

// ---------- weight prep + rope table ----------
__global__ __launch_bounds__(256) void prep_weights(const float* __restrict__ Wq,
                                                    const float* __restrict__ Wk,
                                                    const float* __restrict__ Wv,
                                                    const float* __restrict__ Wo,
                                                    short* __restrict__ Wall,
                                                    short* __restrict__ Wo4,
                                                    float2* __restrict__ RT) {
    int idx = blockIdx.x * 256 + threadIdx.x;   // 262144 = 256 c * 1024 e
    int c = idx >> 10, e = idx & 1023;
    int h = c >> 6, d = c & 63;
    const float* p = Wq + (size_t)e * 1024 + h * 256 + d;   // Wq[e][h*4+g][d]
    Wall[(size_t)c * 1024 + e] = f2bf(0.18033688011112042f * (p[0] + p[64] + p[128] + p[192]));
    Wall[(size_t)(256 + c) * 1024 + e] = f2bf(Wk[(size_t)e * 256 + c]);
    Wall[(size_t)(512 + c) * 1024 + e] = f2bf(Wv[(size_t)e * 256 + c]);
    Wo4[(size_t)e * 256 + c] = f2bf(0.25f * Wo[(size_t)d * 1024 + e]);
    if (idx < 65536) {
        int s = idx >> 5, ii = idx & 31;
        float freq = __expf(-(float)ii * (9.210340371976184f / 32.0f));
        float sn, cs;
        sincosf((float)s * freq, &sn, &cs);
        RT[idx] = (float2){cs, sn};
    }
}

// ---------- fused Q/K/V projection; epilogue LDS-staged for coalesced stores ----------
__global__ __launch_bounds__(256) void proj_kernel(const float* __restrict__ q,
                                                   const float* __restrict__ kv,
                                                   const short* __restrict__ Wall,
                                                   const float2* __restrict__ RT,
                                                   short* __restrict__ Qb,
                                                   short* __restrict__ Kb,
                                                   short* __restrict__ Vt) {
    __shared__ alignas(16) short As[128][72];
    __shared__ alignas(16) short Bs[64][72];
    int tid = threadIdx.x;
    int wave = tid >> 6, lane = tid & 63, quad = lane >> 4, c16 = lane & 15;
    int wm = wave >> 1, wn = wave & 1;
    int m0 = blockIdx.x * 128, n0 = blockIdx.y * 64;
    const float* A = (n0 < 256) ? q : kv;

    f32x4 acc[4][2];
    #pragma unroll
    for (int i = 0; i < 4; i++)
        #pragma unroll
        for (int j = 0; j < 2; j++) acc[i][j] = (f32x4){0.f, 0.f, 0.f, 0.f};

    for (int k0 = 0; k0 < 1024; k0 += 64) {
        #pragma unroll
        for (int i = 0; i < 8; i++) {
            int id = i * 256 + tid, r = id >> 4, ch = id & 15;
            float4 v = *(const float4*)&A[(size_t)(m0 + r) * 1024 + k0 + ch * 4];
            uint2 u;
            u.x = pk_bf16(v.x, v.y);
            u.y = pk_bf16(v.z, v.w);
            *(uint2*)&As[r][ch * 4] = u;
        }
        #pragma unroll
        for (int i = 0; i < 2; i++) {
            int id = i * 256 + tid, r = id >> 3, ch = id & 7;
            *(int4*)&Bs[r][ch * 8] =
                *(const int4*)&Wall[(size_t)(n0 + r) * 1024 + k0 + ch * 8];
        }
        __syncthreads();
        #pragma unroll
        for (int ks = 0; ks < 64; ks += 32) {
            bf16x8 af[4], bfr[2];
            #pragma unroll
            for (int mt = 0; mt < 4; mt++)
                af[mt] = *(const bf16x8*)&As[wm * 64 + mt * 16 + c16][ks + quad * 8];
            #pragma unroll
            for (int nt = 0; nt < 2; nt++)
                bfr[nt] = *(const bf16x8*)&Bs[wn * 32 + nt * 16 + c16][ks + quad * 8];
            #pragma unroll
            for (int mt = 0; mt < 4; mt++)
                #pragma unroll
                for (int nt = 0; nt < 2; nt++)
                    acc[mt][nt] = __builtin_amdgcn_mfma_f32_16x16x32_bf16(
                        af[mt], bfr[nt], acc[mt][nt], 0, 0, 0);
        }
        __syncthreads();   // also frees As for epilogue reuse
    }
    if (n0 < 512) {
        // Q or K: rope in regs -> As[128][72] bf16 -> coalesced row-major stores
        #pragma unroll
        for (int mt = 0; mt < 4; mt++) {
            #pragma unroll
            for (int nt = 0; nt < 2; nt++) {
                int cl = wn * 32 + nt * 16 + c16;       // local col 0..63
                int ii = ((n0 + cl) & 63) >> 1;
                float sgn = (lane & 1) ? 1.0f : -1.0f;
                f32x4 v = acc[mt][nt];
                #pragma unroll
                for (int r = 0; r < 4; r++) {
                    int rl = wm * 64 + mt * 16 + quad * 4 + r;   // local row
                    float2 cs = RT[((m0 + rl) & (SS - 1)) * 32 + ii];
                    float other = __shfl_xor(v[r], 1);
                    As[rl][cl] = f2bf_r(v[r] * cs.x + sgn * cs.y * other);
                }
            }
        }
        __syncthreads();
        short* dstb = (n0 < 256) ? Qb : Kb;
        int nc0 = n0 & 255;
        #pragma unroll
        for (int i = 0; i < 4; i++) {
            int id = i * 256 + tid, r = id >> 3, ch = id & 7;
            *(int4*)&dstb[(size_t)(m0 + r) * 256 + nc0 + ch * 8] =
                *(const int4*)&As[r][ch * 8];
        }
    } else {
        // V: transpose via LDS -> Vt[(b*256+c)][s] coalesced along s
        short (*Lt)[136] = (short(*)[136])&As[0][0];    // 64 c x (128 s + pad)
        #pragma unroll
        for (int mt = 0; mt < 4; mt++) {
            #pragma unroll
            for (int nt = 0; nt < 2; nt++) {
                int cl = wn * 32 + nt * 16 + c16;
                int sl = wm * 64 + mt * 16 + quad * 4;
                f32x4 v = acc[mt][nt];
                uint2 u;
                u.x = pk_bf16(v[0], v[1]);
                u.y = pk_bf16(v[2], v[3]);
                *(uint2*)&Lt[cl][sl] = u;
            }
        }
        __syncthreads();
        int b = m0 >> 11, s0 = m0 & (SS - 1), c0 = n0 - 512;
        #pragma unroll
        for (int i = 0; i < 4; i++) {
            int id = i * 256 + tid, c = id >> 4, ch = id & 15;
            *(int4*)&Vt[((size_t)(b * 256 + c0 + c)) * SS + s0 + ch * 8] =
                *(const int4*)&Lt[c][ch * 8];
        }
    }
}

// ---------- MFMA flash attention, static max, K-split x2, Ps aliased on Qs ----------
__global__ __launch_bounds__(256, 5) void attn_kernel(const short* __restrict__ Qb,
                                                      const short* __restrict__ Kb,
                                                      const short* __restrict__ Vt,
                                                      float* __restrict__ Opart,
                                                      float* __restrict__ Lpart) {
    __shared__ alignas(16) short Qs[64][72];   // Q tile, then per-wave P tiles
    __shared__ alignas(16) short Ks[64][72], Vs[64][72];
    int tid = threadIdx.x;
    int wave = tid >> 6, lane = tid & 63, quad = lane >> 4, c16 = lane & 15;
    int qt = blockIdx.x, bh = blockIdx.y, kc = blockIdx.z;
    int q0 = qt * 64;
    size_t qkbase = (size_t)(bh >> 2) * SS * 256 + (bh & 3) * 64;
    size_t vtbase = (size_t)(bh * 64) * SS;
    size_t pbase  = (size_t)(kc * 16 + bh) * SS;

    #pragma unroll
    for (int i = 0; i < 2; i++) {
        int id = i * 256 + tid, r = id >> 3, ch = id & 7;
        *(int4*)&Qs[r][ch * 8] = *(const int4*)&Qb[qkbase + (size_t)(q0 + r) * 256 + ch * 8];
    }
    __syncthreads();
    // Q A-fragments hoisted; afterwards this wave's 16-row slice of Qs is reused as Ps
    bf16x8 aq0 = *(const bf16x8*)&Qs[wave * 16 + c16][quad * 8];
    bf16x8 aq1 = *(const bf16x8*)&Qs[wave * 16 + c16][32 + quad * 8];
    short (*Ps)[72] = (short (*)[72])Qs[wave * 16];

    float lsum[4] = {0.f, 0.f, 0.f, 0.f};
    f32x4 o[4];
    #pragma unroll
    for (int dt = 0; dt < 4; dt++) o[dt] = (f32x4){0.f, 0.f, 0.f, 0.f};

    for (int kt = 0; kt < 16; kt++) {
        int a0 = kc * 1024 + kt * 64;
        __syncthreads();
        #pragma unroll
        for (int i = 0; i < 2; i++) {
            int id = i * 256 + tid, r = id >> 3, ch = id & 7;
            *(int4*)&Ks[r][ch * 8] =
                *(const int4*)&Kb[qkbase + (size_t)(a0 + r) * 256 + ch * 8];
            *(int4*)&Vs[r][ch * 8] =
                *(const int4*)&Vt[vtbase + (size_t)r * SS + a0 + ch * 8];
        }
        __syncthreads();
        f32x4 sv[4];
        #pragma unroll
        for (int nt = 0; nt < 4; nt++) sv[nt] = (f32x4){0.f, 0.f, 0.f, 0.f};
        #pragma unroll
        for (int nt = 0; nt < 4; nt++) {
            bf16x8 bk0 = *(const bf16x8*)&Ks[nt * 16 + c16][quad * 8];
            bf16x8 bk1 = *(const bf16x8*)&Ks[nt * 16 + c16][32 + quad * 8];
            sv[nt] = __builtin_amdgcn_mfma_f32_16x16x32_bf16(aq0, bk0, sv[nt], 0, 0, 0);
            sv[nt] = __builtin_amdgcn_mfma_f32_16x16x32_bf16(aq1, bk1, sv[nt], 0, 0, 0);
        }
        #pragma unroll
        for (int nt = 0; nt < 4; nt++)
            #pragma unroll
            for (int r = 0; r < 4; r++) sv[nt][r] = __builtin_exp2f(sv[nt][r]);
        #pragma unroll
        for (int r = 0; r < 4; r++)
            lsum[r] += (sv[0][r] + sv[1][r]) + (sv[2][r] + sv[3][r]);
        #pragma unroll
        for (int nt = 0; nt < 4; nt++)
            #pragma unroll
            for (int r = 0; r < 4; r++)
                Ps[quad * 4 + r][nt * 16 + c16] = f2bf_r(sv[nt][r]);
        #pragma unroll
        for (int ks = 0; ks < 64; ks += 32) {
            bf16x8 ap = *(const bf16x8*)&Ps[c16][ks + quad * 8];
            #pragma unroll
            for (int dt = 0; dt < 4; dt++) {
                bf16x8 bv = *(const bf16x8*)&Vs[dt * 16 + c16][ks + quad * 8];
                o[dt] = __builtin_amdgcn_mfma_f32_16x16x32_bf16(ap, bv, o[dt], 0, 0, 0);
            }
        }
    }
    #pragma unroll
    for (int off = 1; off < 16; off <<= 1)
        #pragma unroll
        for (int r = 0; r < 4; r++) lsum[r] += __shfl_xor(lsum[r], off);
    #pragma unroll
    for (int dt = 0; dt < 4; dt++)
        #pragma unroll
        for (int r = 0; r < 4; r++) {
            int row = q0 + wave * 16 + quad * 4 + r;
            Opart[(pbase + row) * 64 + dt * 16 + c16] = o[dt][r];
        }
    if (c16 == 0)
        #pragma unroll
        for (int r = 0; r < 4; r++)
            Lpart[pbase + q0 + wave * 16 + quad * 4 + r] = lsum[r];
}

// ---------- output projection, BM=64 BN=128, fused K-split combine ----------
__global__ __launch_bounds__(256) void outproj_kernel(const float* __restrict__ Op,
                                                      const float* __restrict__ Lp,
                                                      const short* __restrict__ Wo4,
                                                      float* __restrict__ out) {
    __shared__ alignas(16) short As[64][72];
    __shared__ alignas(16) short Bs[128][72];
    int tid = threadIdx.x;
    int wave = tid >> 6, lane = tid & 63, quad = lane >> 4, c16 = lane & 15;
    int wm = wave >> 1, wn = wave & 1;
    int m0 = blockIdx.x * 64, n0 = blockIdx.y * 128;

    f32x4 acc[2][4];
    #pragma unroll
    for (int i = 0; i < 2; i++)
        #pragma unroll
        for (int j = 0; j < 4; j++) acc[i][j] = (f32x4){0.f, 0.f, 0.f, 0.f};

    for (int k0 = 0; k0 < 256; k0 += 64) {
        int h = k0 >> 6;
        #pragma unroll
        for (int i = 0; i < 4; i++) {
            int id = i * 256 + tid, r = id >> 4, ch = id & 15;
            int row = m0 + r, b = row >> 11, s = row & (SS - 1);
            int bh = b * 4 + h;
            size_t pidx = ((size_t)bh * SS + s) * 64 + ch * 4;
            float4 a = *(const float4*)&Op[pidx];
            float4 c = *(const float4*)&Op[pidx + (size_t)16 * SS * 64];
            float l = Lp[(size_t)bh * SS + s] + Lp[(size_t)(16 + bh) * SS + s];
            float rl = __builtin_amdgcn_rcpf(l);
            uint2 u;
            u.x = pk_bf16((a.x + c.x) * rl, (a.y + c.y) * rl);
            u.y = pk_bf16((a.z + c.z) * rl, (a.w + c.w) * rl);
            *(uint2*)&As[r][ch * 4] = u;
        }
        #pragma unroll
        for (int i = 0; i < 4; i++) {
            int id = i * 256 + tid, r = id >> 3, ch = id & 7;
            *(int4*)&Bs[r][ch * 8] =
                *(const int4*)&Wo4[(size_t)(n0 + r) * 256 + k0 + ch * 8];
        }
        __syncthreads();
        #pragma unroll
        for (int ks = 0; ks < 64; ks += 32) {
            bf16x8 af[2], bfr[4];
            #pragma unroll
            for (int mt = 0; mt < 2; mt++)
                af[mt] = *(const bf16x8*)&As[wm * 32 + mt * 16 + c16][ks + quad * 8];
            #pragma unroll
            for (int nt = 0; nt < 4; nt++)
                bfr[nt] = *(const bf16x8*)&Bs[wn * 64 + nt * 16 + c16][ks + quad * 8];
            #pragma unroll
            for (int mt = 0; mt < 2; mt++)
                #pragma unroll
                for (int nt = 0; nt < 4; nt++)
                    acc[mt][nt] = __builtin_amdgcn_mfma_f32_16x16x32_bf16(
                        af[mt], bfr[nt], acc[mt][nt], 0, 0, 0);
        }
        __syncthreads();
    }
    #pragma unroll
    for (int mt = 0; mt < 2; mt++)
        #pragma unroll
        for (int nt = 0; nt < 4; nt++) {
            int col = n0 + wn * 64 + nt * 16 + c16;
            int rowb = m0 + wm * 32 + mt * 16 + quad * 4;
            #pragma unroll
            for (int r = 0; r < 4; r++)
                out[(size_t)(rowb + r) * 1024 + col] = acc[mt][nt][r];
        }
}

extern "C" void kernel_launch(void* const* d_in, const int* in_sizes, int n_in,
                              void* d_out, int out_size, void* d_ws, size_t ws_size,
                              hipStream_t stream) {
    const float* q  = (const float*)d_in[0];
    const float* kv = (const float*)d_in[1];
    const float* Wq = (const float*)d_in[2];
    const float* Wk = (const float*)d_in[3];
    const float* Wv = (const float*)d_in[4];
    const float* Wo = (const float*)d_in[5];
    float* out = (float*)d_out;

    short* Qb    = (short*)d_ws;           // 2097152 bf16
    short* Kb    = Qb + 2097152;           // 2097152
    short* Vt    = Kb + 2097152;           // 2097152 (pre-transposed [b*256+h*64+d][s])
    short* Wall  = Vt + 2097152;           // 786432
    short* Wo4   = Wall + 786432;          // 262144
    float2* RT   = (float2*)(Wo4 + 262144);    // 65536 float2
    float* Opart = (float*)(RT + 65536);   // 4194304 fp32
    float* Lpart = Opart + 4194304;        // 65536 fp32

    prep_weights<<<1024, 256, 0, stream>>>(Wq, Wk, Wv, Wo, Wall, Wo4, RT);

    proj_kernel<<<dim3(64, 12), 256, 0, stream>>>(q, kv, Wall, RT, Qb, Kb, Vt);

    attn_kernel<<<dim3(32, 16, 2), 256, 0, stream>>>(Qb, Kb, Vt, Opart, Lpart);

    outproj_kernel<<<dim3(128, 8), 256, 0, stream>>>(Opart, Lpart, Wo4, out);
}